// Round 6
// baseline (2567.962 us; speedup 1.0000x reference)
//
#include <hip/hip_runtime.h>
#include <cstdint>

// ODEBlock: 16 RK4 steps of f(t,y) = tanh(y@W1 + b1 + t) @ W2 + b2
// B=1024 (M), D=512, H=2048. bf16 MFMA GEMMs, fp32 state/epilogues.
// R6: R2's proven grid-512 tiling + three fixes:
//  - XOR bank-swizzled LDS staging (R3 counters: 5e7 conflicts unswizzled)
//  - gemm2 split-K=4 with fused tail-combine: last split block per tile
//    (device-scope atomic counter) does combine+RK4 in-kernel. 2 launches/
//    stage instead of 3 (195 -> 131).
//  - XCD-pinned weight tiles: bn = blockIdx%8-derived so each XCD re-reads
//    the same 256KB weight slice every stage (L2-resident across launches).

typedef __bf16 bf16x8 __attribute__((ext_vector_type(8)));
typedef float f32x4 __attribute__((ext_vector_type(4)));

#define AS1 __attribute__((address_space(1)))
#define AS3 __attribute__((address_space(3)))

#define MDIM 1024
#define DDIM 512
#define HDIM 2048

__device__ __forceinline__ void async_copy16(const void* g, void* lds) {
  __builtin_amdgcn_global_load_lds((const AS1 void*)g, (AS3 void*)lds, 16, 0, 0);
}

__device__ __forceinline__ unsigned short f32_to_bf16(float f) {
  union { float f; unsigned u; } c; c.f = f;
  unsigned u = c.u + 0x7FFFu + ((c.u >> 16) & 1u);   // RNE
  return (unsigned short)(u >> 16);
}

__device__ __forceinline__ float tanh_fast(float x) {
  float a = __builtin_fabsf(x);
  float e = __expf(-2.0f * a);
  float r = (1.0f - e) * __builtin_amdgcn_rcpf(1.0f + e);
  return __builtin_copysignf(r, x);
}

// ---- transpose + f32->bf16: out[c*R + r] = bf16(in[r*C + c]) --------------
__global__ __launch_bounds__(256) void transpose_bf16_kernel(
    const float* __restrict__ in, unsigned short* __restrict__ out, int R, int C) {
  __shared__ float tile[64][65];
  int nbc = C >> 6;
  int br = blockIdx.x / nbc, bc = blockIdx.x % nbc;
  int r0 = br * 64, c0 = bc * 64;
  int tr = threadIdx.x >> 6, tc = threadIdx.x & 63;
  for (int i = 0; i < 16; ++i) {
    int row = i * 4 + tr;
    tile[row][tc] = in[(r0 + row) * C + c0 + tc];
  }
  __syncthreads();
  for (int i = 0; i < 16; ++i) {
    int row = i * 4 + tr;
    out[(c0 + row) * R + r0 + tc] = f32_to_bf16(tile[tc][row]);
  }
}

// ---- init: y = x (fp32, lives in d_out), arg = bf16(x) --------------------
__global__ __launch_bounds__(256) void init_kernel(
    const float* __restrict__ x, float* __restrict__ y,
    unsigned short* __restrict__ arg) {
  int i = blockIdx.x * 256 + threadIdx.x;
  float v = x[i];
  y[i] = v;
  arg[i] = f32_to_bf16(v);
}

// ---- GEMM1: H = tanh(arg[1024,512] @ W1 + b1 + t) -------------------------
// W1T [2048,512] bf16 (K-contig). Tile 64x64, BK=64, grid 512 (2 blocks/CU),
// 4 waves 2x2, wave 32x32, dbuf, XOR-swizzled staging.
// bn = (bid&7)*4 + ((bid>>3)&3): XCD b%8 always sees the same 256 H-cols.
__global__ __launch_bounds__(256, 2) void gemm1_kernel(
    const unsigned short* __restrict__ A,    // arg bf16 [1024,512]
    const unsigned short* __restrict__ Bt,   // W1T bf16 [2048,512]
    const float* __restrict__ b1, float tval,
    unsigned short* __restrict__ H)          // [1024,2048] bf16
{
  __shared__ bf16x8 sA[2][512];   // 2 x 8KB
  __shared__ bf16x8 sB[2][512];   // 2 x 8KB
  const int K = DDIM;
  const int NITER = DDIM / 64;    // 8
  int bid = blockIdx.x;
  int bn = (bid & 7) * 4 + ((bid >> 3) & 3);   // 0..31
  int bm = bid >> 5;                           // 0..15
  int tid = threadIdx.x;
  int lane = tid & 63;
  int wid = tid >> 6;
  int l15 = lane & 15;
  int l4 = lane >> 4;
  int wm = (wid >> 1) * 32;
  int wn = (wid & 1) * 32;
  int srow = tid >> 3;                              // 0..31
  int skcol = ((tid & 7) ^ (srow & 7)) * 8;         // swizzled k-offset
  const unsigned short* gA = A + (size_t)(bm * 64 + srow) * K + skcol;
  const unsigned short* gB = Bt + (size_t)(bn * 64 + srow) * K + skcol;
  int sw = l15 & 7;
  f32x4 acc[2][2] = {};

  async_copy16(gA, &sA[0][tid]);
  async_copy16(gA + 32 * K, &sA[0][256 + tid]);
  async_copy16(gB, &sB[0][tid]);
  async_copy16(gB + 32 * K, &sB[0][256 + tid]);

#pragma unroll 1
  for (int kt = 0; kt < NITER; ++kt) {
    int cur = kt & 1;
    __syncthreads();
    if (kt + 1 < NITER) {
      int nxt = cur ^ 1;
      int off = (kt + 1) * 64;
      async_copy16(gA + off, &sA[nxt][tid]);
      async_copy16(gA + 32 * K + off, &sA[nxt][256 + tid]);
      async_copy16(gB + off, &sB[nxt][tid]);
      async_copy16(gB + 32 * K + off, &sB[nxt][256 + tid]);
    }
#pragma unroll
    for (int ks = 0; ks < 2; ++ks) {
      int kg = (ks * 4 + l4) ^ sw;
      bf16x8 af[2], bfr[2];
#pragma unroll
      for (int i = 0; i < 2; ++i)
        af[i] = sA[cur][(wm + i * 16 + l15) * 8 + kg];
#pragma unroll
      for (int j = 0; j < 2; ++j)
        bfr[j] = sB[cur][(wn + j * 16 + l15) * 8 + kg];
#pragma unroll
      for (int i = 0; i < 2; ++i)
#pragma unroll
        for (int j = 0; j < 2; ++j)
          acc[i][j] = __builtin_amdgcn_mfma_f32_16x16x32_bf16(
              af[i], bfr[j], acc[i][j], 0, 0, 0);
    }
  }
  int row0 = bm * 64 + wm + l4 * 4;
  int col0 = bn * 64 + wn + l15;
  float bias[2];
#pragma unroll
  for (int j = 0; j < 2; ++j) bias[j] = b1[col0 + j * 16] + tval;
#pragma unroll
  for (int i = 0; i < 2; ++i)
#pragma unroll
    for (int r = 0; r < 4; ++r) {
      unsigned short* Hrow = H + (size_t)(row0 + i * 16 + r) * HDIM + col0;
#pragma unroll
      for (int j = 0; j < 2; ++j)
        Hrow[j * 16] = f32_to_bf16(tanh_fast(acc[i][j][r] + bias[j]));
    }
}

// ---- GEMM2 split-K=4 + fused tail combine/RK4 -----------------------------
// W2T [512,2048] bf16. Tile 64x64, BK=64, 8 iters per 512-K chunk.
// Grid 512: bn = bid&7 (XCD-pinned W2 cols), kc = (bid>>3)&3, bm = bid>>5.
// Each block stores its fp32 partial to part[kc][tile] (contig 16KB), then
// atomically bumps ctr[tile]. The block seeing old == stg*4+3 is last: it
// re-reads all 4 partials (L2-hot, co-XCD) and does the RK4 epilogue.
__global__ __launch_bounds__(256, 2) void gemm2_kernel(
    const unsigned short* __restrict__ A,    // H bf16 [1024,2048]
    const unsigned short* __restrict__ Bt,   // W2T bf16 [512,2048]
    const float* __restrict__ b2,
    float* __restrict__ y, float* __restrict__ kacc,
    unsigned short* __restrict__ arg,
    float* __restrict__ part,                // [4][128 tiles][4096] f32
    unsigned* __restrict__ ctr,              // [128] monotone across stages
    int stg, float dt)
{
  __shared__ bf16x8 sA[2][512];
  __shared__ bf16x8 sB[2][512];
  __shared__ int isLast;
  const int K = HDIM;
  const int NITER = 8;
  int bid = blockIdx.x;
  int bn = bid & 7;                 // 0..7   (XCD-pinned output cols)
  int kc = (bid >> 3) & 3;          // 0..3   split-K chunk
  int bm = bid >> 5;                // 0..15
  int tile = bm * 8 + bn;           // 0..127
  int tid = threadIdx.x;
  int lane = tid & 63;
  int wid = tid >> 6;
  int l15 = lane & 15;
  int l4 = lane >> 4;
  int wm = (wid >> 1) * 32;
  int wn = (wid & 1) * 32;
  int srow = tid >> 3;
  int skcol = ((tid & 7) ^ (srow & 7)) * 8;
  int k0 = kc * 512;
  const unsigned short* gA = A + (size_t)(bm * 64 + srow) * K + k0 + skcol;
  const unsigned short* gB = Bt + (size_t)(bn * 64 + srow) * K + k0 + skcol;
  int sw = l15 & 7;
  f32x4 acc[2][2] = {};

  async_copy16(gA, &sA[0][tid]);
  async_copy16(gA + 32 * K, &sA[0][256 + tid]);
  async_copy16(gB, &sB[0][tid]);
  async_copy16(gB + 32 * K, &sB[0][256 + tid]);

#pragma unroll 1
  for (int kt = 0; kt < NITER; ++kt) {
    int cur = kt & 1;
    __syncthreads();
    if (kt + 1 < NITER) {
      int nxt = cur ^ 1;
      int off = (kt + 1) * 64;
      async_copy16(gA + off, &sA[nxt][tid]);
      async_copy16(gA + 32 * K + off, &sA[nxt][256 + tid]);
      async_copy16(gB + off, &sB[nxt][tid]);
      async_copy16(gB + 32 * K + off, &sB[nxt][256 + tid]);
    }
#pragma unroll
    for (int ks = 0; ks < 2; ++ks) {
      int kg = (ks * 4 + l4) ^ sw;
      bf16x8 af[2], bfr[2];
#pragma unroll
      for (int i = 0; i < 2; ++i)
        af[i] = sA[cur][(wm + i * 16 + l15) * 8 + kg];
#pragma unroll
      for (int j = 0; j < 2; ++j)
        bfr[j] = sB[cur][(wn + j * 16 + l15) * 8 + kg];
#pragma unroll
      for (int i = 0; i < 2; ++i)
#pragma unroll
        for (int j = 0; j < 2; ++j)
          acc[i][j] = __builtin_amdgcn_mfma_f32_16x16x32_bf16(
              af[i], bfr[j], acc[i][j], 0, 0, 0);
    }
  }

  // store fp32 partial to contiguous per-tile buffer
  float* Pt = part + ((size_t)(kc * 128 + tile) << 12);
  int lrow0 = wm + l4 * 4;
  int lcol0 = wn + l15;
#pragma unroll
  for (int i = 0; i < 2; ++i)
#pragma unroll
    for (int r = 0; r < 4; ++r) {
      float* Prow = Pt + (lrow0 + i * 16 + r) * 64 + lcol0;
#pragma unroll
      for (int j = 0; j < 2; ++j)
        Prow[j * 16] = acc[i][j][r];
    }

  __syncthreads();   // all waves' partial stores complete (vmcnt drained)
  if (tid == 0) {
    unsigned old = __hip_atomic_fetch_add(&ctr[tile], 1u, __ATOMIC_ACQ_REL,
                                          __HIP_MEMORY_SCOPE_AGENT);
    isLast = (old == (unsigned)stg * 4u + 3u) ? 1 : 0;
  }
  __syncthreads();
  if (!isLast) return;

  // ---- tail: combine 4 partials + RK4 epilogue for this 64x64 tile -------
  int mode = stg & 3;
  float half_dt = 0.5f * dt;
  float dt6 = dt * (1.0f / 6.0f);
  const float4* P0 = (const float4*)(part + ((size_t)(0 * 128 + tile) << 12));
  const float4* P1 = (const float4*)(part + ((size_t)(1 * 128 + tile) << 12));
  const float4* P2 = (const float4*)(part + ((size_t)(2 * 128 + tile) << 12));
  const float4* P3 = (const float4*)(part + ((size_t)(3 * 128 + tile) << 12));
#pragma unroll
  for (int q = 0; q < 4; ++q) {
    int le4 = q * 256 + tid;              // float4 index within tile, 0..1023
    int lrow = le4 >> 4;
    int lc = (le4 & 15) * 4;
    int grow = bm * 64 + lrow;
    int gcol = bn * 64 + lc;
    float4 p0 = P0[le4], p1 = P1[le4], p2 = P2[le4], p3 = P3[le4];
    float4 bb = *(const float4*)(b2 + gcol);
    float4 k;
    k.x = p0.x + p1.x + p2.x + p3.x + bb.x;
    k.y = p0.y + p1.y + p2.y + p3.y + bb.y;
    k.z = p0.z + p1.z + p2.z + p3.z + bb.z;
    k.w = p0.w + p1.w + p2.w + p3.w + bb.w;
    int e = grow * DDIM + gcol;
    float4 yv = *(const float4*)(y + e);
    float4 argv;
    if (mode == 0) {
      *(float4*)(kacc + e) = k;
      argv.x = yv.x + half_dt * k.x; argv.y = yv.y + half_dt * k.y;
      argv.z = yv.z + half_dt * k.z; argv.w = yv.w + half_dt * k.w;
    } else if (mode == 1) {
      float4 ka = *(const float4*)(kacc + e);
      ka.x += 2.0f * k.x; ka.y += 2.0f * k.y;
      ka.z += 2.0f * k.z; ka.w += 2.0f * k.w;
      *(float4*)(kacc + e) = ka;
      argv.x = yv.x + half_dt * k.x; argv.y = yv.y + half_dt * k.y;
      argv.z = yv.z + half_dt * k.z; argv.w = yv.w + half_dt * k.w;
    } else if (mode == 2) {
      float4 ka = *(const float4*)(kacc + e);
      ka.x += 2.0f * k.x; ka.y += 2.0f * k.y;
      ka.z += 2.0f * k.z; ka.w += 2.0f * k.w;
      *(float4*)(kacc + e) = ka;
      argv.x = yv.x + dt * k.x; argv.y = yv.y + dt * k.y;
      argv.z = yv.z + dt * k.z; argv.w = yv.w + dt * k.w;
    } else {
      float4 ka = *(const float4*)(kacc + e);
      argv.x = yv.x + dt6 * (ka.x + k.x); argv.y = yv.y + dt6 * (ka.y + k.y);
      argv.z = yv.z + dt6 * (ka.z + k.z); argv.w = yv.w + dt6 * (ka.w + k.w);
      *(float4*)(y + e) = argv;
    }
    ushort4 av;
    av.x = f32_to_bf16(argv.x); av.y = f32_to_bf16(argv.y);
    av.z = f32_to_bf16(argv.z); av.w = f32_to_bf16(argv.w);
    *(ushort4*)(arg + e) = av;
  }
}

extern "C" void kernel_launch(void* const* d_in, const int* in_sizes, int n_in,
                              void* d_out, int out_size, void* d_ws, size_t ws_size,
                              hipStream_t stream) {
  (void)in_sizes; (void)n_in; (void)out_size; (void)ws_size;
  const float* x  = (const float*)d_in[0];   // [1024,512]
  const float* W1 = (const float*)d_in[1];   // [512,2048]
  const float* b1 = (const float*)d_in[2];   // [2048]
  const float* W2 = (const float*)d_in[3];   // [2048,512]
  const float* b2 = (const float*)d_in[4];   // [512]
  float* y = (float*)d_out;                  // fp32 state lives in d_out

  char* ws = (char*)d_ws;
  unsigned short* W1T  = (unsigned short*)(ws);                 // 2MB
  unsigned short* W2T  = (unsigned short*)(ws + (2u << 20));    // 2MB
  unsigned short* Hbuf = (unsigned short*)(ws + (4u << 20));    // 4MB
  unsigned short* arg  = (unsigned short*)(ws + (8u << 20));    // 1MB
  float*          kacc = (float*)(ws + (9u << 20));             // 2MB
  float*          part = (float*)(ws + (11u << 20));            // 8MB
  unsigned*       ctr  = (unsigned*)(ws + (19u << 20));         // 512B
  // total ~19MB

  hipMemsetAsync(ctr, 0, 128 * sizeof(unsigned), stream);
  transpose_bf16_kernel<<<256, 256, 0, stream>>>(W1, W1T, DDIM, HDIM);
  transpose_bf16_kernel<<<256, 256, 0, stream>>>(W2, W2T, HDIM, DDIM);
  init_kernel<<<MDIM * DDIM / 256, 256, 0, stream>>>(x, y, arg);

  const float dt = 1.0f / 16.0f;
  for (int n = 0; n < 16; ++n) {
    float t0 = dt * (float)n;
    const float ts[4] = {t0, t0 + 0.5f * dt, t0 + 0.5f * dt, t0 + dt};
    for (int s = 0; s < 4; ++s) {
      int stg = n * 4 + s;
      gemm1_kernel<<<512, 256, 0, stream>>>(arg, W1T, b1, ts[s], Hbuf);
      gemm2_kernel<<<512, 256, 0, stream>>>(Hbuf, W2T, b2, y, kacc, arg,
                                            part, ctr, stg, dt);
    }
  }
}

// Round 7
// 1425.656 us; speedup vs baseline: 1.8012x; 1.8012x over previous
//
#include <hip/hip_runtime.h>
#include <cstdint>

// ODEBlock: 16 RK4 steps of f(t,y) = tanh(y@W1 + b1 + t) @ W2 + b2
// B=1024 (M), D=512, H=2048. bf16 MFMA GEMMs, fp32 state/epilogues.
// R7 = R2 (best known: 1593us) + ONE change: XOR bank-swizzle on LDS staging
// in both gemm kernels (R3 counter: 5e7 LDS conflicts for this layout family;
// 16-way conflict on every ds_read_b128 = 5.7x LDS slowdown per m136).
// Everything else is byte-identical to R2: 64x64 tiles grid 512, split-K=4
// gemm2, separate combine kernel, no atomics, no XCD remaps.

typedef __bf16 bf16x8 __attribute__((ext_vector_type(8)));
typedef float f32x4 __attribute__((ext_vector_type(4)));

#define AS1 __attribute__((address_space(1)))
#define AS3 __attribute__((address_space(3)))

#define MDIM 1024
#define DDIM 512
#define HDIM 2048

__device__ __forceinline__ void async_copy16(const void* g, void* lds) {
  __builtin_amdgcn_global_load_lds((const AS1 void*)g, (AS3 void*)lds, 16, 0, 0);
}

__device__ __forceinline__ unsigned short f32_to_bf16(float f) {
  union { float f; unsigned u; } c; c.f = f;
  unsigned u = c.u + 0x7FFFu + ((c.u >> 16) & 1u);   // RNE
  return (unsigned short)(u >> 16);
}

__device__ __forceinline__ float tanh_fast(float x) {
  float a = __builtin_fabsf(x);
  float e = __expf(-2.0f * a);                        // in (0,1], no overflow
  float r = (1.0f - e) * __builtin_amdgcn_rcpf(1.0f + e);
  return __builtin_copysignf(r, x);
}

// ---- transpose + f32->bf16: out[c*R + r] = bf16(in[r*C + c]) --------------
__global__ __launch_bounds__(256) void transpose_bf16_kernel(
    const float* __restrict__ in, unsigned short* __restrict__ out, int R, int C) {
  __shared__ float tile[64][65];
  int nbc = C >> 6;
  int br = blockIdx.x / nbc, bc = blockIdx.x % nbc;
  int r0 = br * 64, c0 = bc * 64;
  int tr = threadIdx.x >> 6, tc = threadIdx.x & 63;
  for (int i = 0; i < 16; ++i) {
    int row = i * 4 + tr;
    tile[row][tc] = in[(r0 + row) * C + c0 + tc];
  }
  __syncthreads();
  for (int i = 0; i < 16; ++i) {
    int row = i * 4 + tr;
    out[(c0 + row) * R + r0 + tc] = f32_to_bf16(tile[tc][row]);
  }
}

// ---- init: y = x (fp32, lives in d_out), arg = bf16(x) --------------------
__global__ __launch_bounds__(256) void init_kernel(
    const float* __restrict__ x, float* __restrict__ y,
    unsigned short* __restrict__ arg) {
  int i = blockIdx.x * 256 + threadIdx.x;
  float v = x[i];
  y[i] = v;
  arg[i] = f32_to_bf16(v);
}

// ---- GEMM1: H = tanh(arg[1024,512] @ W1 + b1 + t) -------------------------
// W1T [2048,512] bf16 (K-contig). Tile 64x64, BK=64, grid 16x32=512 blocks,
// 4 waves (2x2), wave 32x32, LDS double-buffer. XOR-swizzled staging:
// LDS unit u (row=u>>3, slot=u&7) holds global k-group (slot ^ (row&7)).
__global__ __launch_bounds__(256, 2) void gemm1_kernel(
    const unsigned short* __restrict__ A,    // arg bf16 [1024,512]
    const unsigned short* __restrict__ Bt,   // W1T bf16 [2048,512]
    const float* __restrict__ b1, float tval,
    unsigned short* __restrict__ H)          // [1024,2048] bf16
{
  __shared__ bf16x8 sA[2][512];   // 2 x 8KB
  __shared__ bf16x8 sB[2][512];   // 2 x 8KB
  const int K = DDIM;
  const int NITER = DDIM / 64;    // 8
  int bid = blockIdx.x;
  int bm = bid >> 5;              // 0..15
  int bn = bid & 31;              // 0..31
  int tid = threadIdx.x;
  int lane = tid & 63;
  int wid = tid >> 6;
  int l15 = lane & 15;
  int l4 = lane >> 4;
  int wm = (wid >> 1) * 32;
  int wn = (wid & 1) * 32;
  int srow = tid >> 3;                              // 0..31
  int skcol = ((tid & 7) ^ (srow & 7)) * 8;         // swizzled k-offset (elems)
  const unsigned short* gA = A + (size_t)(bm * 64 + srow) * K + skcol;
  const unsigned short* gB = Bt + (size_t)(bn * 64 + srow) * K + skcol;
  int sw = l15 & 7;                                 // read-side swizzle
  f32x4 acc[2][2] = {};

  async_copy16(gA, &sA[0][tid]);
  async_copy16(gA + 32 * K, &sA[0][256 + tid]);
  async_copy16(gB, &sB[0][tid]);
  async_copy16(gB + 32 * K, &sB[0][256 + tid]);

#pragma unroll 1
  for (int kt = 0; kt < NITER; ++kt) {
    int cur = kt & 1;
    __syncthreads();
    if (kt + 1 < NITER) {
      int nxt = cur ^ 1;
      int off = (kt + 1) * 64;
      async_copy16(gA + off, &sA[nxt][tid]);
      async_copy16(gA + 32 * K + off, &sA[nxt][256 + tid]);
      async_copy16(gB + off, &sB[nxt][tid]);
      async_copy16(gB + 32 * K + off, &sB[nxt][256 + tid]);
    }
#pragma unroll
    for (int ks = 0; ks < 2; ++ks) {
      int kg = (ks * 4 + l4) ^ sw;
      bf16x8 af[2], bfr[2];
#pragma unroll
      for (int i = 0; i < 2; ++i)
        af[i] = sA[cur][(wm + i * 16 + l15) * 8 + kg];
#pragma unroll
      for (int j = 0; j < 2; ++j)
        bfr[j] = sB[cur][(wn + j * 16 + l15) * 8 + kg];
#pragma unroll
      for (int i = 0; i < 2; ++i)
#pragma unroll
        for (int j = 0; j < 2; ++j)
          acc[i][j] = __builtin_amdgcn_mfma_f32_16x16x32_bf16(
              af[i], bfr[j], acc[i][j], 0, 0, 0);
    }
  }
  // D(m,n): m = l4*4 + reg, n = l15
  int row0 = bm * 64 + wm + l4 * 4;
  int col0 = bn * 64 + wn + l15;
  float bias[2];
  for (int j = 0; j < 2; ++j) bias[j] = b1[col0 + j * 16] + tval;
#pragma unroll
  for (int i = 0; i < 2; ++i)
#pragma unroll
    for (int r = 0; r < 4; ++r) {
      unsigned short* Hrow = H + (size_t)(row0 + i * 16 + r) * HDIM + col0;
#pragma unroll
      for (int j = 0; j < 2; ++j)
        Hrow[j * 16] = f32_to_bf16(tanh_fast(acc[i][j][r] + bias[j]));
    }
}

// ---- GEMM2 split-K: part[s] = H[:, s*512:(s+1)*512] @ W2T'[:, chunk] ------
// W2T [512,2048] bf16. Tile 64x64, BK=64, splitK=4, grid 4*16*8=512 blocks.
__global__ __launch_bounds__(256, 2) void gemm2_kernel(
    const unsigned short* __restrict__ A,    // H bf16 [1024,2048]
    const unsigned short* __restrict__ Bt,   // W2T bf16 [512,2048]
    float* __restrict__ part)                // [4][1024,512] fp32
{
  __shared__ bf16x8 sA[2][512];
  __shared__ bf16x8 sB[2][512];
  const int K = HDIM;
  const int NITER = 8;                 // 512 K-chunk / 64
  int bid = blockIdx.x;
  int s = bid >> 7;                    // split-K index 0..3
  int rem = bid & 127;
  int bm = rem >> 3;                   // 0..15
  int bn = rem & 7;                    // 0..7
  int tid = threadIdx.x;
  int lane = tid & 63;
  int wid = tid >> 6;
  int l15 = lane & 15;
  int l4 = lane >> 4;
  int wm = (wid >> 1) * 32;
  int wn = (wid & 1) * 32;
  int srow = tid >> 3;
  int skcol = ((tid & 7) ^ (srow & 7)) * 8;
  int k0 = s * 512;
  const unsigned short* gA = A + (size_t)(bm * 64 + srow) * K + k0 + skcol;
  const unsigned short* gB = Bt + (size_t)(bn * 64 + srow) * K + k0 + skcol;
  int sw = l15 & 7;
  f32x4 acc[2][2] = {};

  async_copy16(gA, &sA[0][tid]);
  async_copy16(gA + 32 * K, &sA[0][256 + tid]);
  async_copy16(gB, &sB[0][tid]);
  async_copy16(gB + 32 * K, &sB[0][256 + tid]);

#pragma unroll 1
  for (int kt = 0; kt < NITER; ++kt) {
    int cur = kt & 1;
    __syncthreads();
    if (kt + 1 < NITER) {
      int nxt = cur ^ 1;
      int off = (kt + 1) * 64;
      async_copy16(gA + off, &sA[nxt][tid]);
      async_copy16(gA + 32 * K + off, &sA[nxt][256 + tid]);
      async_copy16(gB + off, &sB[nxt][tid]);
      async_copy16(gB + 32 * K + off, &sB[nxt][256 + tid]);
    }
#pragma unroll
    for (int ks = 0; ks < 2; ++ks) {
      int kg = (ks * 4 + l4) ^ sw;
      bf16x8 af[2], bfr[2];
#pragma unroll
      for (int i = 0; i < 2; ++i)
        af[i] = sA[cur][(wm + i * 16 + l15) * 8 + kg];
#pragma unroll
      for (int j = 0; j < 2; ++j)
        bfr[j] = sB[cur][(wn + j * 16 + l15) * 8 + kg];
#pragma unroll
      for (int i = 0; i < 2; ++i)
#pragma unroll
        for (int j = 0; j < 2; ++j)
          acc[i][j] = __builtin_amdgcn_mfma_f32_16x16x32_bf16(
              af[i], bfr[j], acc[i][j], 0, 0, 0);
    }
  }
  int row0 = bm * 64 + wm + l4 * 4;
  int col0 = bn * 64 + wn + l15;
  float* P = part + (size_t)s * (MDIM * DDIM);
#pragma unroll
  for (int i = 0; i < 2; ++i)
#pragma unroll
    for (int r = 0; r < 4; ++r) {
      float* Prow = P + (size_t)(row0 + i * 16 + r) * DDIM + col0;
#pragma unroll
      for (int j = 0; j < 2; ++j)
        Prow[j * 16] = acc[i][j][r];
    }
}

// ---- combine + RK4 epilogue (vectorized float4 / ushort4) -----------------
// k = p0+p1+p2+p3 + b2
// mode 0: kacc = k;            arg = bf16(y + dt/2*k)
// mode 1: kacc += 2k;          arg = bf16(y + dt/2*k)
// mode 2: kacc += 2k;          arg = bf16(y + dt*k)
// mode 3: y += dt/6*(kacc+k);  arg = bf16(y_new)
__global__ __launch_bounds__(256) void combine_rk4_kernel(
    const float* __restrict__ part,          // [4][1024*512]
    const float* __restrict__ b2,
    float* __restrict__ y, float* __restrict__ kacc,
    unsigned short* __restrict__ arg, int mode, float dt)
{
  int t = blockIdx.x * 256 + threadIdx.x;    // 0..131071
  int base = t * 4;
  int col = base & (DDIM - 1);
  const float4* p0 = (const float4*)(part);
  const float4* p1 = (const float4*)(part + MDIM * DDIM);
  const float4* p2 = (const float4*)(part + 2 * MDIM * DDIM);
  const float4* p3 = (const float4*)(part + 3 * MDIM * DDIM);
  float4 a = p0[t], b = p1[t], c = p2[t], d = p3[t];
  float4 bb = *(const float4*)(b2 + col);
  float4 k;
  k.x = a.x + b.x + c.x + d.x + bb.x;
  k.y = a.y + b.y + c.y + d.y + bb.y;
  k.z = a.z + b.z + c.z + d.z + bb.z;
  k.w = a.w + b.w + c.w + d.w + bb.w;
  float4 yv = *(const float4*)(y + base);
  float4 argv;
  if (mode == 0) {
    *(float4*)(kacc + base) = k;
    float h = 0.5f * dt;
    argv.x = yv.x + h * k.x; argv.y = yv.y + h * k.y;
    argv.z = yv.z + h * k.z; argv.w = yv.w + h * k.w;
  } else if (mode == 1) {
    float4 ka = *(const float4*)(kacc + base);
    ka.x += 2.0f * k.x; ka.y += 2.0f * k.y; ka.z += 2.0f * k.z; ka.w += 2.0f * k.w;
    *(float4*)(kacc + base) = ka;
    float h = 0.5f * dt;
    argv.x = yv.x + h * k.x; argv.y = yv.y + h * k.y;
    argv.z = yv.z + h * k.z; argv.w = yv.w + h * k.w;
  } else if (mode == 2) {
    float4 ka = *(const float4*)(kacc + base);
    ka.x += 2.0f * k.x; ka.y += 2.0f * k.y; ka.z += 2.0f * k.z; ka.w += 2.0f * k.w;
    *(float4*)(kacc + base) = ka;
    argv.x = yv.x + dt * k.x; argv.y = yv.y + dt * k.y;
    argv.z = yv.z + dt * k.z; argv.w = yv.w + dt * k.w;
  } else {
    float4 ka = *(const float4*)(kacc + base);
    float sx = dt * (1.0f / 6.0f);
    argv.x = yv.x + sx * (ka.x + k.x); argv.y = yv.y + sx * (ka.y + k.y);
    argv.z = yv.z + sx * (ka.z + k.z); argv.w = yv.w + sx * (ka.w + k.w);
    *(float4*)(y + base) = argv;
  }
  ushort4 av;
  av.x = f32_to_bf16(argv.x); av.y = f32_to_bf16(argv.y);
  av.z = f32_to_bf16(argv.z); av.w = f32_to_bf16(argv.w);
  *(ushort4*)(arg + base) = av;
}

extern "C" void kernel_launch(void* const* d_in, const int* in_sizes, int n_in,
                              void* d_out, int out_size, void* d_ws, size_t ws_size,
                              hipStream_t stream) {
  (void)in_sizes; (void)n_in; (void)out_size; (void)ws_size;
  const float* x  = (const float*)d_in[0];   // [1024,512]
  const float* W1 = (const float*)d_in[1];   // [512,2048]
  const float* b1 = (const float*)d_in[2];   // [2048]
  const float* W2 = (const float*)d_in[3];   // [2048,512]
  const float* b2 = (const float*)d_in[4];   // [512]
  float* y = (float*)d_out;                  // fp32 state lives in d_out

  char* ws = (char*)d_ws;
  unsigned short* W1T  = (unsigned short*)(ws);                    // 2MB  [2048,512] bf16
  unsigned short* W2T  = (unsigned short*)(ws + (2u << 20));       // 2MB  [512,2048] bf16
  unsigned short* Hbuf = (unsigned short*)(ws + (4u << 20));       // 4MB  [1024,2048] bf16
  unsigned short* arg  = (unsigned short*)(ws + (8u << 20));       // 1MB  [1024,512] bf16
  float*          kacc = (float*)(ws + (9u << 20));                // 2MB  [1024,512] f32
  float*          part = (float*)(ws + (11u << 20));               // 8MB  [4][1024,512] f32
  // total 19MB

  transpose_bf16_kernel<<<256, 256, 0, stream>>>(W1, W1T, DDIM, HDIM);
  transpose_bf16_kernel<<<256, 256, 0, stream>>>(W2, W2T, HDIM, DDIM);
  init_kernel<<<MDIM * DDIM / 256, 256, 0, stream>>>(x, y, arg);

  const float dt = 1.0f / 16.0f;
  for (int n = 0; n < 16; ++n) {
    float t0 = dt * (float)n;
    const float ts[4] = {t0, t0 + 0.5f * dt, t0 + 0.5f * dt, t0 + dt};
    for (int s = 0; s < 4; ++s) {
      gemm1_kernel<<<512, 256, 0, stream>>>(arg, W1T, b1, ts[s], Hbuf);
      gemm2_kernel<<<512, 256, 0, stream>>>(Hbuf, W2T, part);
      combine_rk4_kernel<<<512, 256, 0, stream>>>(part, b2, y, kacc, arg, s, dt);
    }
  }
}

// Round 8
// 1294.282 us; speedup vs baseline: 1.9841x; 1.1015x over previous
//
#include <hip/hip_runtime.h>
#include <cstdint>

// ODEBlock: 16 RK4 steps of f(t,y) = tanh(y@W1 + b1 + t) @ W2 + b2
// B=1024 (M), D=512, H=2048. bf16 MFMA GEMMs, fp32 state/epilogues.
// R8 = R7 (best: 1425us) + ONE change: BK 64 -> 128 in both GEMM kernels
// (4 K-iters instead of 8 -> half the vmcnt(0)-before-barrier drains, the
// dominant modeled stall). 64KB dynamic LDS/block, grid stays 512 =
// 2 blocks/CU (128KB/CU <= 160KB). Same tiles/swizzle/combine/K-order ->
// bit-identical output (absmax must stay exactly 0.03125).

typedef __bf16 bf16x8 __attribute__((ext_vector_type(8)));
typedef float f32x4 __attribute__((ext_vector_type(4)));

#define AS1 __attribute__((address_space(1)))
#define AS3 __attribute__((address_space(3)))

#define MDIM 1024
#define DDIM 512
#define HDIM 2048

#define GEMM_LDS (64 * 1024)   // sA 2x16KB + sB 2x16KB

__device__ __forceinline__ void async_copy16(const void* g, void* lds) {
  __builtin_amdgcn_global_load_lds((const AS1 void*)g, (AS3 void*)lds, 16, 0, 0);
}

__device__ __forceinline__ unsigned short f32_to_bf16(float f) {
  union { float f; unsigned u; } c; c.f = f;
  unsigned u = c.u + 0x7FFFu + ((c.u >> 16) & 1u);   // RNE
  return (unsigned short)(u >> 16);
}

__device__ __forceinline__ float tanh_fast(float x) {
  float a = __builtin_fabsf(x);
  float e = __expf(-2.0f * a);                        // in (0,1], no overflow
  float r = (1.0f - e) * __builtin_amdgcn_rcpf(1.0f + e);
  return __builtin_copysignf(r, x);
}

// ---- transpose + f32->bf16: out[c*R + r] = bf16(in[r*C + c]) --------------
__global__ __launch_bounds__(256) void transpose_bf16_kernel(
    const float* __restrict__ in, unsigned short* __restrict__ out, int R, int C) {
  __shared__ float tile[64][65];
  int nbc = C >> 6;
  int br = blockIdx.x / nbc, bc = blockIdx.x % nbc;
  int r0 = br * 64, c0 = bc * 64;
  int tr = threadIdx.x >> 6, tc = threadIdx.x & 63;
  for (int i = 0; i < 16; ++i) {
    int row = i * 4 + tr;
    tile[row][tc] = in[(r0 + row) * C + c0 + tc];
  }
  __syncthreads();
  for (int i = 0; i < 16; ++i) {
    int row = i * 4 + tr;
    out[(c0 + row) * R + r0 + tc] = f32_to_bf16(tile[tc][row]);
  }
}

// ---- init: y = x (fp32, lives in d_out), arg = bf16(x) --------------------
__global__ __launch_bounds__(256) void init_kernel(
    const float* __restrict__ x, float* __restrict__ y,
    unsigned short* __restrict__ arg) {
  int i = blockIdx.x * 256 + threadIdx.x;
  float v = x[i];
  y[i] = v;
  arg[i] = f32_to_bf16(v);
}

// ---- GEMM1: H = tanh(arg[1024,512] @ W1 + b1 + t) -------------------------
// W1T [2048,512] bf16 (K-contig). Tile 64x64, BK=128, 4 K-iters, grid 512
// (2 blocks/CU), 4 waves 2x2, wave 32x32, LDS dbuf 64KB. XOR-swizzled
// staging: unit u (row=u>>4, slot=u&15) holds global k-group (slot^(row&7)).
__global__ __launch_bounds__(256, 2) void gemm1_kernel(
    const unsigned short* __restrict__ A,    // arg bf16 [1024,512]
    const unsigned short* __restrict__ Bt,   // W1T bf16 [2048,512]
    const float* __restrict__ b1, float tval,
    unsigned short* __restrict__ H)          // [1024,2048] bf16
{
  extern __shared__ char ldsbuf[];
  bf16x8* sA = (bf16x8*)ldsbuf;              // 2 x 1024 units (32KB)
  bf16x8* sB = (bf16x8*)(ldsbuf + 32768);    // 2 x 1024 units (32KB)
  const int K = DDIM;
  const int NITER = 4;            // 512 / 128
  int bid = blockIdx.x;
  int bm = bid >> 5;              // 0..15
  int bn = bid & 31;              // 0..31
  int tid = threadIdx.x;
  int lane = tid & 63;
  int wid = tid >> 6;
  int l15 = lane & 15;
  int l4 = lane >> 4;
  int wm = (wid >> 1) * 32;
  int wn = (wid & 1) * 32;
  int sw = l15 & 7;               // read-side swizzle (row & 7)

  // staging: 4 units per thread per matrix (1024 units = 64 rows x 16 slots)
  const unsigned short* gA[4];
  const unsigned short* gB[4];
#pragma unroll
  for (int i = 0; i < 4; ++i) {
    int u = tid + i * 256, r = u >> 4, s = u & 15;
    int koff = ((s ^ (r & 7)) * 8);
    gA[i] = A + (size_t)(bm * 64 + r) * K + koff;
    gB[i] = Bt + (size_t)(bn * 64 + r) * K + koff;
  }
  f32x4 acc[2][2] = {};

#pragma unroll
  for (int i = 0; i < 4; ++i) {
    async_copy16(gA[i], &sA[tid + i * 256]);
    async_copy16(gB[i], &sB[tid + i * 256]);
  }

#pragma unroll 1
  for (int kt = 0; kt < NITER; ++kt) {
    int cur = kt & 1;
    __syncthreads();
    if (kt + 1 < NITER) {
      int nxt = cur ^ 1;
      int off = (kt + 1) * 128;
#pragma unroll
      for (int i = 0; i < 4; ++i) {
        async_copy16(gA[i] + off, &sA[nxt * 1024 + tid + i * 256]);
        async_copy16(gB[i] + off, &sB[nxt * 1024 + tid + i * 256]);
      }
    }
#pragma unroll
    for (int ks = 0; ks < 4; ++ks) {
      int kg = (ks * 4 + l4) ^ sw;
      bf16x8 af[2], bfr[2];
#pragma unroll
      for (int i = 0; i < 2; ++i)
        af[i] = sA[cur * 1024 + (wm + i * 16 + l15) * 16 + kg];
#pragma unroll
      for (int j = 0; j < 2; ++j)
        bfr[j] = sB[cur * 1024 + (wn + j * 16 + l15) * 16 + kg];
#pragma unroll
      for (int i = 0; i < 2; ++i)
#pragma unroll
        for (int j = 0; j < 2; ++j)
          acc[i][j] = __builtin_amdgcn_mfma_f32_16x16x32_bf16(
              af[i], bfr[j], acc[i][j], 0, 0, 0);
    }
  }
  // D(m,n): m = l4*4 + reg, n = l15
  int row0 = bm * 64 + wm + l4 * 4;
  int col0 = bn * 64 + wn + l15;
  float bias[2];
  for (int j = 0; j < 2; ++j) bias[j] = b1[col0 + j * 16] + tval;
#pragma unroll
  for (int i = 0; i < 2; ++i)
#pragma unroll
    for (int r = 0; r < 4; ++r) {
      unsigned short* Hrow = H + (size_t)(row0 + i * 16 + r) * HDIM + col0;
#pragma unroll
      for (int j = 0; j < 2; ++j)
        Hrow[j * 16] = f32_to_bf16(tanh_fast(acc[i][j][r] + bias[j]));
    }
}

// ---- GEMM2 split-K: part[s] = H[:, s*512:(s+1)*512] @ W2T'[:, chunk] ------
// W2T [512,2048] bf16. Tile 64x64, BK=128, 4 iters per 512-K chunk,
// splitK=4, grid 512. Same staging/swizzle as gemm1.
__global__ __launch_bounds__(256, 2) void gemm2_kernel(
    const unsigned short* __restrict__ A,    // H bf16 [1024,2048]
    const unsigned short* __restrict__ Bt,   // W2T bf16 [512,2048]
    float* __restrict__ part)                // [4][1024,512] fp32
{
  extern __shared__ char ldsbuf[];
  bf16x8* sA = (bf16x8*)ldsbuf;
  bf16x8* sB = (bf16x8*)(ldsbuf + 32768);
  const int K = HDIM;
  const int NITER = 4;                 // 512 K-chunk / 128
  int bid = blockIdx.x;
  int s = bid >> 7;                    // split-K index 0..3
  int rem = bid & 127;
  int bm = rem >> 3;                   // 0..15
  int bn = rem & 7;                    // 0..7
  int tid = threadIdx.x;
  int lane = tid & 63;
  int wid = tid >> 6;
  int l15 = lane & 15;
  int l4 = lane >> 4;
  int wm = (wid >> 1) * 32;
  int wn = (wid & 1) * 32;
  int sw = l15 & 7;
  int k0 = s * 512;

  const unsigned short* gA[4];
  const unsigned short* gB[4];
#pragma unroll
  for (int i = 0; i < 4; ++i) {
    int u = tid + i * 256, r = u >> 4, sl = u & 15;
    int koff = ((sl ^ (r & 7)) * 8);
    gA[i] = A + (size_t)(bm * 64 + r) * K + k0 + koff;
    gB[i] = Bt + (size_t)(bn * 64 + r) * K + k0 + koff;
  }
  f32x4 acc[2][2] = {};

#pragma unroll
  for (int i = 0; i < 4; ++i) {
    async_copy16(gA[i], &sA[tid + i * 256]);
    async_copy16(gB[i], &sB[tid + i * 256]);
  }

#pragma unroll 1
  for (int kt = 0; kt < NITER; ++kt) {
    int cur = kt & 1;
    __syncthreads();
    if (kt + 1 < NITER) {
      int nxt = cur ^ 1;
      int off = (kt + 1) * 128;
#pragma unroll
      for (int i = 0; i < 4; ++i) {
        async_copy16(gA[i] + off, &sA[nxt * 1024 + tid + i * 256]);
        async_copy16(gB[i] + off, &sB[nxt * 1024 + tid + i * 256]);
      }
    }
#pragma unroll
    for (int ks = 0; ks < 4; ++ks) {
      int kg = (ks * 4 + l4) ^ sw;
      bf16x8 af[2], bfr[2];
#pragma unroll
      for (int i = 0; i < 2; ++i)
        af[i] = sA[cur * 1024 + (wm + i * 16 + l15) * 16 + kg];
#pragma unroll
      for (int j = 0; j < 2; ++j)
        bfr[j] = sB[cur * 1024 + (wn + j * 16 + l15) * 16 + kg];
#pragma unroll
      for (int i = 0; i < 2; ++i)
#pragma unroll
        for (int j = 0; j < 2; ++j)
          acc[i][j] = __builtin_amdgcn_mfma_f32_16x16x32_bf16(
              af[i], bfr[j], acc[i][j], 0, 0, 0);
    }
  }
  int row0 = bm * 64 + wm + l4 * 4;
  int col0 = bn * 64 + wn + l15;
  float* P = part + (size_t)s * (MDIM * DDIM);
#pragma unroll
  for (int i = 0; i < 2; ++i)
#pragma unroll
    for (int r = 0; r < 4; ++r) {
      float* Prow = P + (size_t)(row0 + i * 16 + r) * DDIM + col0;
#pragma unroll
      for (int j = 0; j < 2; ++j)
        Prow[j * 16] = acc[i][j][r];
    }
}

// ---- combine + RK4 epilogue (vectorized float4 / ushort4) -----------------
// k = p0+p1+p2+p3 + b2
// mode 0: kacc = k;            arg = bf16(y + dt/2*k)
// mode 1: kacc += 2k;          arg = bf16(y + dt/2*k)
// mode 2: kacc += 2k;          arg = bf16(y + dt*k)
// mode 3: y += dt/6*(kacc+k);  arg = bf16(y_new)
__global__ __launch_bounds__(256) void combine_rk4_kernel(
    const float* __restrict__ part,          // [4][1024*512]
    const float* __restrict__ b2,
    float* __restrict__ y, float* __restrict__ kacc,
    unsigned short* __restrict__ arg, int mode, float dt)
{
  int t = blockIdx.x * 256 + threadIdx.x;    // 0..131071
  int base = t * 4;
  int col = base & (DDIM - 1);
  const float4* p0 = (const float4*)(part);
  const float4* p1 = (const float4*)(part + MDIM * DDIM);
  const float4* p2 = (const float4*)(part + 2 * MDIM * DDIM);
  const float4* p3 = (const float4*)(part + 3 * MDIM * DDIM);
  float4 a = p0[t], b = p1[t], c = p2[t], d = p3[t];
  float4 bb = *(const float4*)(b2 + col);
  float4 k;
  k.x = a.x + b.x + c.x + d.x + bb.x;
  k.y = a.y + b.y + c.y + d.y + bb.y;
  k.z = a.z + b.z + c.z + d.z + bb.z;
  k.w = a.w + b.w + c.w + d.w + bb.w;
  float4 yv = *(const float4*)(y + base);
  float4 argv;
  if (mode == 0) {
    *(float4*)(kacc + base) = k;
    float h = 0.5f * dt;
    argv.x = yv.x + h * k.x; argv.y = yv.y + h * k.y;
    argv.z = yv.z + h * k.z; argv.w = yv.w + h * k.w;
  } else if (mode == 1) {
    float4 ka = *(const float4*)(kacc + base);
    ka.x += 2.0f * k.x; ka.y += 2.0f * k.y; ka.z += 2.0f * k.z; ka.w += 2.0f * k.w;
    *(float4*)(kacc + base) = ka;
    float h = 0.5f * dt;
    argv.x = yv.x + h * k.x; argv.y = yv.y + h * k.y;
    argv.z = yv.z + h * k.z; argv.w = yv.w + h * k.w;
  } else if (mode == 2) {
    float4 ka = *(const float4*)(kacc + base);
    ka.x += 2.0f * k.x; ka.y += 2.0f * k.y; ka.z += 2.0f * k.z; ka.w += 2.0f * k.w;
    *(float4*)(kacc + base) = ka;
    argv.x = yv.x + dt * k.x; argv.y = yv.y + dt * k.y;
    argv.z = yv.z + dt * k.z; argv.w = yv.w + dt * k.w;
  } else {
    float4 ka = *(const float4*)(kacc + base);
    float sx = dt * (1.0f / 6.0f);
    argv.x = yv.x + sx * (ka.x + k.x); argv.y = yv.y + sx * (ka.y + k.y);
    argv.z = yv.z + sx * (ka.z + k.z); argv.w = yv.w + sx * (ka.w + k.w);
    *(float4*)(y + base) = argv;
  }
  ushort4 av;
  av.x = f32_to_bf16(argv.x); av.y = f32_to_bf16(argv.y);
  av.z = f32_to_bf16(argv.z); av.w = f32_to_bf16(argv.w);
  *(ushort4*)(arg + base) = av;
}

extern "C" void kernel_launch(void* const* d_in, const int* in_sizes, int n_in,
                              void* d_out, int out_size, void* d_ws, size_t ws_size,
                              hipStream_t stream) {
  (void)in_sizes; (void)n_in; (void)out_size; (void)ws_size;
  const float* x  = (const float*)d_in[0];   // [1024,512]
  const float* W1 = (const float*)d_in[1];   // [512,2048]
  const float* b1 = (const float*)d_in[2];   // [2048]
  const float* W2 = (const float*)d_in[3];   // [2048,512]
  const float* b2 = (const float*)d_in[4];   // [512]
  float* y = (float*)d_out;                  // fp32 state lives in d_out

  char* ws = (char*)d_ws;
  unsigned short* W1T  = (unsigned short*)(ws);                    // 2MB  [2048,512] bf16
  unsigned short* W2T  = (unsigned short*)(ws + (2u << 20));       // 2MB  [512,2048] bf16
  unsigned short* Hbuf = (unsigned short*)(ws + (4u << 20));       // 4MB  [1024,2048] bf16
  unsigned short* arg  = (unsigned short*)(ws + (8u << 20));       // 1MB  [1024,512] bf16
  float*          kacc = (float*)(ws + (9u << 20));                // 2MB  [1024,512] f32
  float*          part = (float*)(ws + (11u << 20));               // 8MB  [4][1024,512] f32
  // total 19MB

  hipFuncSetAttribute((const void*)gemm1_kernel,
                      hipFuncAttributeMaxDynamicSharedMemorySize, GEMM_LDS);
  hipFuncSetAttribute((const void*)gemm2_kernel,
                      hipFuncAttributeMaxDynamicSharedMemorySize, GEMM_LDS);

  transpose_bf16_kernel<<<256, 256, 0, stream>>>(W1, W1T, DDIM, HDIM);
  transpose_bf16_kernel<<<256, 256, 0, stream>>>(W2, W2T, HDIM, DDIM);
  init_kernel<<<MDIM * DDIM / 256, 256, 0, stream>>>(x, y, arg);

  const float dt = 1.0f / 16.0f;
  for (int n = 0; n < 16; ++n) {
    float t0 = dt * (float)n;
    const float ts[4] = {t0, t0 + 0.5f * dt, t0 + 0.5f * dt, t0 + dt};
    for (int s = 0; s < 4; ++s) {
      gemm1_kernel<<<512, 256, GEMM_LDS, stream>>>(arg, W1T, b1, ts[s], Hbuf);
      gemm2_kernel<<<512, 256, GEMM_LDS, stream>>>(Hbuf, W2T, part);
      combine_rk4_kernel<<<512, 256, 0, stream>>>(part, b2, y, kacc, arg, s, dt);
    }
  }
}